// Round 1
// baseline (1339.322 us; speedup 1.0000x reference)
//
#include <hip/hip_runtime.h>
#include <hip/hip_bf16.h>

#define NB    16384   // batch
#define NR    2048    // memory rows
#define NC    128     // memory cols (= key dim)
#define KCTRL 1024    // controller dim
#define NH    134     // NC + 6
#define EPSF  1e-16f

__device__ __forceinline__ float softplus_f(float x) {
    // stable: max(x,0) + log1p(exp(-|x|))
    return fmaxf(x, 0.f) + log1pf(__expf(-fabsf(x)));
}

// ---------------- K0: M row norms ----------------
__global__ __launch_bounds__(64) void mnorm_kernel(const float* __restrict__ M,
                                                   float* __restrict__ mnorm) {
    const int i = blockIdx.x;
    const int lane = threadIdx.x;
    float a = M[(size_t)i * NC + lane];
    float b = M[(size_t)i * NC + 64 + lane];
    float s = a * a + b * b;
    #pragma unroll
    for (int m = 1; m < 64; m <<= 1) s += __shfl_xor(s, m);
    if (lane == 0) mnorm[i] = sqrtf(s);
}

// ---------------- K1: h = x @ W_fc + b_fc ----------------
// 8 batch rows per block; thread j owns output column j.
// x reads are wave-uniform -> compiler emits scalar loads (s_load) feeding
// v_fmac with an SGPR operand; W reads are coalesced across j.
__global__ __launch_bounds__(192) void fc_kernel(const float* __restrict__ x,
                                                 const float* __restrict__ Wfc,
                                                 const float* __restrict__ bfc,
                                                 float* __restrict__ k_buf,
                                                 float* __restrict__ h6) {
    const int b0 = blockIdx.x * 8;
    const int j = threadIdx.x;
    if (j >= NH) return;

    float acc[8];
    #pragma unroll
    for (int r = 0; r < 8; r++) acc[r] = 0.f;

    for (int k = 0; k < KCTRL; k += 4) {
        float w0 = Wfc[(size_t)(k + 0) * NH + j];
        float w1 = Wfc[(size_t)(k + 1) * NH + j];
        float w2 = Wfc[(size_t)(k + 2) * NH + j];
        float w3 = Wfc[(size_t)(k + 3) * NH + j];
        #pragma unroll
        for (int r = 0; r < 8; r++) {
            const float4 xv = *(const float4*)(x + (size_t)(b0 + r) * KCTRL + k);
            acc[r] = fmaf(xv.x, w0, acc[r]);
            acc[r] = fmaf(xv.y, w1, acc[r]);
            acc[r] = fmaf(xv.z, w2, acc[r]);
            acc[r] = fmaf(xv.w, w3, acc[r]);
        }
    }
    const float bb = bfc[j];
    #pragma unroll
    for (int r = 0; r < 8; r++) {
        float v = acc[r] + bb;
        if (j < NC) k_buf[(size_t)(b0 + r) * NC + j] = v;
        else        h6[(size_t)(b0 + r) * 6 + (j - NC)] = v;
    }
}

// ---------------- K2: per-row scalars ----------------
// scal[b][8] = {beta, g, s0, s1, s2, gamma, knorm, 0}
__global__ __launch_bounds__(64) void scal_kernel(const float* __restrict__ k_buf,
                                                  const float* __restrict__ h6,
                                                  float* __restrict__ scal) {
    const int b = blockIdx.x;
    const int lane = threadIdx.x;
    float a = k_buf[(size_t)b * NC + lane];
    float c = k_buf[(size_t)b * NC + 64 + lane];
    float s = a * a + c * c;
    #pragma unroll
    for (int m = 1; m < 64; m <<= 1) s += __shfl_xor(s, m);
    if (lane == 0) {
        const float* h = h6 + (size_t)b * 6;
        float beta = softplus_f(h[0]);
        float g = 1.f / (1.f + __expf(-h[1]));
        float m3 = fmaxf(h[2], fmaxf(h[3], h[4]));
        float e0 = __expf(h[2] - m3), e1 = __expf(h[3] - m3), e2 = __expf(h[4] - m3);
        float inv = 1.f / (e0 + e1 + e2);
        float gamma = 1.f + softplus_f(h[5]);
        float* sc = scal + (size_t)b * 8;
        sc[0] = beta; sc[1] = g; sc[2] = e0 * inv; sc[3] = e1 * inv;
        sc[4] = e2 * inv; sc[5] = gamma; sc[6] = sqrtf(s); sc[7] = 0.f;
    }
}

// ---------------- K3: fused head ----------------
// 8 batch rows (tb=0..7) per block, 256 threads.
// Phase 1 : E[tb][i] = exp(beta * cossim(k_tb, M_i))  (bf16 in LDS), S[tb]=sum E
// Phase1.5: w_g = g*E/S + (1-g)*w_prev ; shift by s ; pow gamma ; Z = sum   (in-place)
// Phase 2 : r[tb][:] = (w_pow @ M) / Z
__global__ __launch_bounds__(256) void head_kernel(const float* __restrict__ M,
                                                   const float* __restrict__ mnorm,
                                                   const float* __restrict__ k_buf,
                                                   const float* __restrict__ scal,
                                                   const float* __restrict__ wprev,
                                                   float* __restrict__ out) {
    __shared__ __hip_bfloat16 E_s[8][NR];   // 32 KB
    __shared__ float scal_s[8][8];
    __shared__ float wred[8][4];
    __shared__ float fac_a[8], fac_c[8], invZ_s[8];

    const int tid = threadIdx.x;
    const int b0 = blockIdx.x * 8;

    if (tid < 64) scal_s[tid >> 3][tid & 7] = scal[(size_t)(b0 + (tid >> 3)) * 8 + (tid & 7)];
    __syncthreads();

    // ---- phase 1 ----
    float Sp[8];
    #pragma unroll
    for (int tb = 0; tb < 8; tb++) Sp[tb] = 0.f;

    for (int ot = 0; ot < 4; ot++) {
        const int ia = tid + 512 * ot;
        const int ib = ia + 256;
        const float mna = mnorm[ia], mnb = mnorm[ib];
        float da[8], db[8];
        #pragma unroll
        for (int tb = 0; tb < 8; tb++) { da[tb] = 0.f; db[tb] = 0.f; }
        const float* Ma = M + (size_t)ia * NC;
        const float* Mb = M + (size_t)ib * NC;
        for (int c = 0; c < NC; c += 4) {
            const float4 a4 = *(const float4*)(Ma + c);
            const float4 b4 = *(const float4*)(Mb + c);
            #pragma unroll
            for (int tb = 0; tb < 8; tb++) {
                // wave-uniform address -> scalar load
                const float4 k4 = *(const float4*)(k_buf + (size_t)(b0 + tb) * NC + c);
                da[tb] = fmaf(k4.x, a4.x, da[tb]); da[tb] = fmaf(k4.y, a4.y, da[tb]);
                da[tb] = fmaf(k4.z, a4.z, da[tb]); da[tb] = fmaf(k4.w, a4.w, da[tb]);
                db[tb] = fmaf(k4.x, b4.x, db[tb]); db[tb] = fmaf(k4.y, b4.y, db[tb]);
                db[tb] = fmaf(k4.z, b4.z, db[tb]); db[tb] = fmaf(k4.w, b4.w, db[tb]);
            }
        }
        #pragma unroll
        for (int tb = 0; tb < 8; tb++) {
            const float beta = scal_s[tb][0], knorm = scal_s[tb][6];
            const float ea = __expf(beta * da[tb] / (knorm * mna + EPSF));
            const float eb = __expf(beta * db[tb] / (knorm * mnb + EPSF));
            E_s[tb][ia] = __float2bfloat16(ea);
            E_s[tb][ib] = __float2bfloat16(eb);
            Sp[tb] += ea + eb;
        }
    }
    #pragma unroll
    for (int tb = 0; tb < 8; tb++) {
        #pragma unroll
        for (int m = 1; m < 64; m <<= 1) Sp[tb] += __shfl_xor(Sp[tb], m);
    }
    if ((tid & 63) == 0) {
        const int w = tid >> 6;
        #pragma unroll
        for (int tb = 0; tb < 8; tb++) wred[tb][w] = Sp[tb];
    }
    __syncthreads();
    if (tid < 8) {
        const float S = wred[tid][0] + wred[tid][1] + wred[tid][2] + wred[tid][3];
        const float g = scal_s[tid][1];
        fac_a[tid] = g / S;
        fac_c[tid] = 1.f - g;
    }
    // boundary values of E needed by the in-place shift (read BEFORE overwrite)
    const int tb15 = tid >> 5;           // 8 rows x 32 chunks of 64
    const int c0 = (tid & 31) * 64;
    const float eL = __bfloat162float(E_s[tb15][(c0 + NR - 1) & (NR - 1)]);
    const float eR = __bfloat162float(E_s[tb15][(c0 + 64) & (NR - 1)]);
    __syncthreads();

    // ---- phase 1.5: in-place w_tilde^gamma ----
    {
        const float s0 = scal_s[tb15][2], s1 = scal_s[tb15][3], s2 = scal_s[tb15][4];
        const float gm = scal_s[tb15][5];
        const float fa = fac_a[tb15], fc = fac_c[tb15];
        const float* wp = wprev + (size_t)(b0 + tb15) * NR;

        float em1 = eL;
        float e0v = __bfloat162float(E_s[tb15][c0]);
        float wpm1 = wp[(c0 + NR - 1) & (NR - 1)];
        float wp0 = wp[c0];
        float wgm1 = fa * em1 + fc * wpm1;
        float wg0  = fa * e0v + fc * wp0;
        float Zp = 0.f;
        for (int n = 0; n < 64; n++) {
            const int i = c0 + n;
            const float ep1 = (n == 63) ? eR : __bfloat162float(E_s[tb15][i + 1]);
            const float wpp1 = wp[(i + 1) & (NR - 1)];
            const float wgp1 = fa * ep1 + fc * wpp1;
            const float wt = fmaf(s0, wgm1, fmaf(s1, wg0, s2 * wgp1)) + EPSF;
            const float pw = __expf(gm * __logf(wt));   // wt > 0 always
            Zp += pw;
            E_s[tb15][i] = __float2bfloat16(pw);        // safe: only this thread reads E[i] after
            wgm1 = wg0; wg0 = wgp1;
        }
        #pragma unroll
        for (int m = 1; m < 32; m <<= 1) Zp += __shfl_xor(Zp, m);
        if ((tid & 31) == 0) invZ_s[tb15] = 1.f / Zp;
    }
    __syncthreads();

    // ---- phase 2: r = (w_pow @ M) * invZ ----
    {
        const int jj = (tid & 63) << 1;      // 2 output cols
        const int tbA = (tid >> 6) << 1;     // 2 batch rows
        const int tbB = tbA + 1;
        float aA0 = 0.f, aA1 = 0.f, aB0 = 0.f, aB1 = 0.f;
        for (int i = 0; i < NR; i += 2) {
            const float2 m0 = *(const float2*)(M + (size_t)i * NC + jj);
            const float2 m1 = *(const float2*)(M + (size_t)(i + 1) * NC + jj);
            const __hip_bfloat162 evA = *(const __hip_bfloat162*)(&E_s[tbA][i]);
            const __hip_bfloat162 evB = *(const __hip_bfloat162*)(&E_s[tbB][i]);
            const float eA0 = __low2float(evA), eA1 = __high2float(evA);
            const float eB0 = __low2float(evB), eB1 = __high2float(evB);
            aA0 = fmaf(eA0, m0.x, aA0); aA1 = fmaf(eA0, m0.y, aA1);
            aA0 = fmaf(eA1, m1.x, aA0); aA1 = fmaf(eA1, m1.y, aA1);
            aB0 = fmaf(eB0, m0.x, aB0); aB1 = fmaf(eB0, m0.y, aB1);
            aB0 = fmaf(eB1, m1.x, aB0); aB1 = fmaf(eB1, m1.y, aB1);
        }
        const float zA = invZ_s[tbA], zB = invZ_s[tbB];
        float2 oA; oA.x = aA0 * zA; oA.y = aA1 * zA;
        float2 oB; oB.x = aB0 * zB; oB.y = aB1 * zB;
        *(float2*)(out + (size_t)(b0 + tbA) * NC + jj) = oA;
        *(float2*)(out + (size_t)(b0 + tbB) * NC + jj) = oB;
    }
}

extern "C" void kernel_launch(void* const* d_in, const int* in_sizes, int n_in,
                              void* d_out, int out_size, void* d_ws, size_t ws_size,
                              hipStream_t stream) {
    const float* x     = (const float*)d_in[0];
    const float* Wfc   = (const float*)d_in[1];
    const float* bfc   = (const float*)d_in[2];
    const float* M     = (const float*)d_in[3];
    const float* wprev = (const float*)d_in[4];
    float* out = (float*)d_out;

    char* ws = (char*)d_ws;
    float* k_buf = (float*)(ws);                       // 16384*128*4  = 8388608
    float* h6    = (float*)(ws + 8388608);             // 16384*6*4    = 393216
    float* scal  = (float*)(ws + 8781824);             // 16384*8*4    = 524288
    float* mnorm = (float*)(ws + 9306112);             // 2048*4       = 8192

    hipLaunchKernelGGL(mnorm_kernel, dim3(NR), dim3(64), 0, stream, M, mnorm);
    hipLaunchKernelGGL(fc_kernel, dim3(NB / 8), dim3(192), 0, stream, x, Wfc, bfc, k_buf, h6);
    hipLaunchKernelGGL(scal_kernel, dim3(NB), dim3(64), 0, stream, k_buf, h6, scal);
    hipLaunchKernelGGL(head_kernel, dim3(NB / 8), dim3(256), 0, stream,
                       M, mnorm, k_buf, scal, wprev, out);
}